// Round 2
// baseline (1508.691 us; speedup 1.0000x reference)
//
#include <hip/hip_runtime.h>
#include <math.h>

#define BSZ 8
#define NN 20000
#define F_IN 256
#define H 8
#define D 64
#define E 160000

typedef _Float16 half_t;
typedef float  fx4 __attribute__((ext_vector_type(4)));
typedef int    ix4 __attribute__((ext_vector_type(4)));

// ---------------------------------------------------------------------------
// Kernel 1: fold W_proj with the per-(b,h) scoring vectors.
//   w_src[b][h][f] = sum_d W_proj[(h*D+d)*F_IN + f] * scoring_src[b,0,h,d]
// Grid: 64 blocks (b*8+h), 256 threads (one per f). Tiny (~1M MACs, ~3 us).
// ---------------------------------------------------------------------------
__global__ __launch_bounds__(256) void fold_weights(
        const float* __restrict__ W_proj,   // [H*D][F_IN]
        const float* __restrict__ s_src,    // [BSZ][1][H][D]
        const float* __restrict__ s_trg,
        float* __restrict__ w_src,          // [BSZ][H][F_IN]
        float* __restrict__ w_trg) {
    __shared__ float ls[D];
    __shared__ float lt[D];
    const int b = blockIdx.x >> 3;
    const int h = blockIdx.x & 7;
    const int f = threadIdx.x;
    if (threadIdx.x < D) {
        ls[threadIdx.x] = s_src[((size_t)b * H + h) * D + threadIdx.x];
        lt[threadIdx.x] = s_trg[((size_t)b * H + h) * D + threadIdx.x];
    }
    __syncthreads();
    float as = 0.f, at = 0.f;
#pragma unroll 8
    for (int d = 0; d < D; ++d) {
        const float wp = W_proj[((size_t)(h * D + d)) * F_IN + f];  // coalesced over f
        as = fmaf(wp, ls[d], as);
        at = fmaf(wp, lt[d], at);
    }
    w_src[((size_t)b * H + h) * F_IN + f] = as;
    w_trg[((size_t)b * H + h) * F_IN + f] = at;
}

// ---------------------------------------------------------------------------
// Kernel 2: per-node, per-head scores.
// R1 rewrite: NO LDS row staging. The 8 lanes sharing a row (h=0..7) read
// identical global addresses -> wave-broadcast, one request; the 4
// consecutive fx4 reads per 64B line are L1-served. Each thread handles 4
// rows against one weight fragment, so weight ds_reads are amortized:
// 128 ds_read_b128 / 4 rows = 32 per row (vs 192/row before, 6x fewer).
// LDS = weights only (16.6 KB, RPAD=260 keeps 8-head b128 reads on 8
// disjoint bank groups). Expected limiter: HBM stream (~164 MB once).
// ---------------------------------------------------------------------------
#define RPAD 260
#define TILE_ROWS 128            // 32 thread-groups * 4 rows
#define NT_TILES 157             // ceil(20000 / 128)

__global__ __launch_bounds__(256, 4) void node_scores(
        const float* __restrict__ ch,      // [BSZ][NN][F_IN]
        const float* __restrict__ w_src,   // [BSZ][H][F_IN]
        const float* __restrict__ w_trg,
        half_t* __restrict__ sc_src,       // [BSZ*NN*H] fp16
        half_t* __restrict__ sc_trg) {
    __shared__ float lws[H][RPAD];
    __shared__ float lwt[H][RPAD];

    const int b = blockIdx.x / NT_TILES;
    const int tile = blockIdx.x % NT_TILES;

    // Stage folded weights: 2*8*256 floats, coalesced, once per block.
    const float* gws = w_src + (size_t)b * H * F_IN;
    const float* gwt = w_trg + (size_t)b * H * F_IN;
    for (int i = threadIdx.x; i < H * F_IN; i += 256) {
        lws[i >> 8][i & 255] = gws[i];
        lwt[i >> 8][i & 255] = gwt[i];
    }
    __syncthreads();

    const int h = threadIdx.x & 7;
    const int g = threadIdx.x >> 3;            // 0..31
    const int row0 = tile * TILE_ROWS + g * 4; // first of this thread's 4 rows

    // Clamped row pointers (tail tile 156 has 96 ghost rows; loads clamp,
    // stores are guarded).
    const fx4* rp[4];
    int rows[4];
#pragma unroll
    for (int r = 0; r < 4; ++r) {
        const int rr = row0 + r;
        rows[r] = rr;
        const int rc = rr < NN ? rr : NN - 1;
        rp[r] = (const fx4*)(ch + ((size_t)b * NN + rc) * F_IN);
    }

    const fx4* __restrict__ ws4 = (const fx4*)(&lws[h][0]);
    const fx4* __restrict__ wt4 = (const fx4*)(&lwt[h][0]);

    float as[4] = {0.f, 0.f, 0.f, 0.f};
    float at[4] = {0.f, 0.f, 0.f, 0.f};

#pragma unroll
    for (int f16 = 0; f16 < F_IN / 16; ++f16) {   // 16 iters, 64B/row each
        // weight fragment for this f-range: 8 ds_read_b128, conflict-free
        fx4 s0 = ws4[f16 * 4 + 0], s1 = ws4[f16 * 4 + 1];
        fx4 s2 = ws4[f16 * 4 + 2], s3 = ws4[f16 * 4 + 3];
        fx4 t0 = wt4[f16 * 4 + 0], t1 = wt4[f16 * 4 + 1];
        fx4 t2 = wt4[f16 * 4 + 2], t3 = wt4[f16 * 4 + 3];
#pragma unroll
        for (int r = 0; r < 4; ++r) {
            // whole 64B line of row r, back-to-back (MSHR-merged, L1-hit)
            const fx4 c0 = rp[r][f16 * 4 + 0];
            const fx4 c1 = rp[r][f16 * 4 + 1];
            const fx4 c2 = rp[r][f16 * 4 + 2];
            const fx4 c3 = rp[r][f16 * 4 + 3];
            float a = as[r], t = at[r];
            a = fmaf(c0.x, s0.x, a); a = fmaf(c0.y, s0.y, a);
            a = fmaf(c0.z, s0.z, a); a = fmaf(c0.w, s0.w, a);
            a = fmaf(c1.x, s1.x, a); a = fmaf(c1.y, s1.y, a);
            a = fmaf(c1.z, s1.z, a); a = fmaf(c1.w, s1.w, a);
            a = fmaf(c2.x, s2.x, a); a = fmaf(c2.y, s2.y, a);
            a = fmaf(c2.z, s2.z, a); a = fmaf(c2.w, s2.w, a);
            a = fmaf(c3.x, s3.x, a); a = fmaf(c3.y, s3.y, a);
            a = fmaf(c3.z, s3.z, a); a = fmaf(c3.w, s3.w, a);
            t = fmaf(c0.x, t0.x, t); t = fmaf(c0.y, t0.y, t);
            t = fmaf(c0.z, t0.z, t); t = fmaf(c0.w, t0.w, t);
            t = fmaf(c1.x, t1.x, t); t = fmaf(c1.y, t1.y, t);
            t = fmaf(c1.z, t1.z, t); t = fmaf(c1.w, t1.w, t);
            t = fmaf(c2.x, t2.x, t); t = fmaf(c2.y, t2.y, t);
            t = fmaf(c2.z, t2.z, t); t = fmaf(c2.w, t2.w, t);
            t = fmaf(c3.x, t3.x, t); t = fmaf(c3.y, t3.y, t);
            t = fmaf(c3.z, t3.z, t); t = fmaf(c3.w, t3.w, t);
            as[r] = a; at[r] = t;
        }
    }

#pragma unroll
    for (int r = 0; r < 4; ++r) {
        if (rows[r] < NN) {
            const size_t oi = ((size_t)b * NN + rows[r]) * H + h;
            sc_src[oi] = (half_t)as[r];
            sc_trg[oi] = (half_t)at[r];
        }
    }
}

// ---------------------------------------------------------------------------
// Kernel 3: lift (global gather) + sigmoid. 4 edges per thread. Indices and
// output are streamed non-temporally so the fp16 score tables (5.1 MB total)
// stay resident in L2/L3 for the random gathers.
// ---------------------------------------------------------------------------
__global__ __launch_bounds__(256) void gather_sigmoid(
        const ix4* __restrict__ head4,
        const ix4* __restrict__ tail4,
        const half_t* __restrict__ sc_src,
        const half_t* __restrict__ sc_trg,
        fx4* __restrict__ out4, int total4) {
    const int i = blockIdx.x * 256 + threadIdx.x;
    if (i < total4) {
        const ix4 hh = __builtin_nontemporal_load(&head4[i]);
        const ix4 tt = __builtin_nontemporal_load(&tail4[i]);
        fx4 r;
        r.x = (float)sc_src[hh.x] + (float)sc_trg[tt.x];
        r.y = (float)sc_src[hh.y] + (float)sc_trg[tt.y];
        r.z = (float)sc_src[hh.z] + (float)sc_trg[tt.z];
        r.w = (float)sc_src[hh.w] + (float)sc_trg[tt.w];
        r.x = 1.f / (1.f + __expf(-r.x));
        r.y = 1.f / (1.f + __expf(-r.y));
        r.z = 1.f / (1.f + __expf(-r.z));
        r.w = 1.f / (1.f + __expf(-r.w));
        __builtin_nontemporal_store(r, &out4[i]);
    }
}

extern "C" void kernel_launch(void* const* d_in, const int* in_sizes, int n_in,
                              void* d_out, int out_size, void* d_ws, size_t ws_size,
                              hipStream_t stream) {
    const float* ch   = (const float*)d_in[0];   // [8][20000][256] f32
    const int*   head = (const int*)d_in[1];     // [8][160000] int
    const int*   tail = (const int*)d_in[2];     // [8][160000] int
    const float* W    = (const float*)d_in[3];   // [512][256] f32
    const float* ssrc = (const float*)d_in[4];   // [8][1][8][64] f32
    const float* strg = (const float*)d_in[5];   // [8][1][8][64] f32
    float* out = (float*)d_out;                  // [8][160000] f32

    float* ws = (float*)d_ws;
    float* w_src  = ws;                                   // 16384 floats
    float* w_trg  = ws + BSZ * H * F_IN;                  // 16384 floats
    half_t* sc_src = (half_t*)(ws + 2 * BSZ * H * F_IN);  // 1,280,000 halves
    half_t* sc_trg = sc_src + (size_t)BSZ * NN * H;       // 1,280,000 halves

    fold_weights<<<BSZ * H, 256, 0, stream>>>(W, ssrc, strg, w_src, w_trg);
    node_scores<<<BSZ * NT_TILES, 256, 0, stream>>>(ch, w_src, w_trg, sc_src, sc_trg);
    const int total4 = (BSZ * E) / 4;                     // 320000
    gather_sigmoid<<<(total4 + 255) / 256, 256, 0, stream>>>(
        (const ix4*)head, (const ix4*)tail, sc_src, sc_trg, (fx4*)out, total4);
}

// Round 3
// 320.825 us; speedup vs baseline: 4.7025x; 4.7025x over previous
//
#include <hip/hip_runtime.h>
#include <math.h>

#define BSZ 8
#define NN 20000
#define F_IN 256
#define H 8
#define D 64
#define E 160000

typedef _Float16 half_t;
typedef float  fx4 __attribute__((ext_vector_type(4)));
typedef int    ix4 __attribute__((ext_vector_type(4)));

// ---------------------------------------------------------------------------
// Kernel 1: fold W_proj with the per-(b,h) scoring vectors.
//   w_src[b][h][f] = sum_d W_proj[(h*D+d)*F_IN + f] * scoring_src[b,0,h,d]
// Grid: 64 blocks (b*8+h), 256 threads (one per f). Tiny (~1M MACs, ~3 us).
// ---------------------------------------------------------------------------
__global__ __launch_bounds__(256) void fold_weights(
        const float* __restrict__ W_proj,   // [H*D][F_IN]
        const float* __restrict__ s_src,    // [BSZ][1][H][D]
        const float* __restrict__ s_trg,
        float* __restrict__ w_src,          // [BSZ][H][F_IN]
        float* __restrict__ w_trg) {
    __shared__ float ls[D];
    __shared__ float lt[D];
    const int b = blockIdx.x >> 3;
    const int h = blockIdx.x & 7;
    const int f = threadIdx.x;
    if (threadIdx.x < D) {
        ls[threadIdx.x] = s_src[((size_t)b * H + h) * D + threadIdx.x];
        lt[threadIdx.x] = s_trg[((size_t)b * H + h) * D + threadIdx.x];
    }
    __syncthreads();
    float as = 0.f, at = 0.f;
#pragma unroll 8
    for (int d = 0; d < D; ++d) {
        const float wp = W_proj[((size_t)(h * D + d)) * F_IN + f];  // coalesced over f
        as = fmaf(wp, ls[d], as);
        at = fmaf(wp, lt[d], at);
    }
    w_src[((size_t)b * H + h) * F_IN + f] = as;
    w_trg[((size_t)b * H + h) * F_IN + f] = at;
}

// ---------------------------------------------------------------------------
// Kernel 2: per-node, per-head scores.
// R2: rows read DIRECTLY from global (no LDS row staging). The 8 lanes that
// share a row (h=0..7) read identical 16B addresses in the same instruction
// -> coalescer merges to one request; each 16B of ch is fetched exactly once.
// Each thread handles 2 consecutive rows so the weight ds_read_b128s are
// amortized (16 LDS wave-instrs/row vs 24 in the staging version), and the
// 32-row staging writes + extra barrier disappear.
// R1 post-mortem guardrails: launch_bounds min-waves=2 (VGPR cap 256, the
// (256,4) cap=128 forced a 1.5 GB scratch round-trip), rolled loop with
// unroll 4 (live set ~100 VGPR), no pointer arrays.
// LDS = weights only: 2*8*260*4 = 16.6 KB. RPAD=260 keeps the 8-head b128
// broadcast reads on 8 disjoint 4-bank groups (conflict-free).
// Accumulate in fx4 vector form (packed-f32 FMA if the ISA has it).
// ---------------------------------------------------------------------------
#define RPAD 260
#define TILE_ROWS 64             // 32 thread-groups * 2 rows
#define NT_TILES 313             // ceil(20000 / 64)

__global__ __launch_bounds__(256, 2) void node_scores(
        const float* __restrict__ ch,      // [BSZ][NN][F_IN]
        const float* __restrict__ w_src,   // [BSZ][H][F_IN]
        const float* __restrict__ w_trg,
        half_t* __restrict__ sc_src,       // [BSZ*NN*H] fp16
        half_t* __restrict__ sc_trg) {
    __shared__ float lws[H][RPAD];
    __shared__ float lwt[H][RPAD];

    const int b = blockIdx.x / NT_TILES;
    const int tile = blockIdx.x % NT_TILES;

    // Stage folded weights: 2*8*256 floats, coalesced, once per block.
    const float* gws = w_src + (size_t)b * H * F_IN;
    const float* gwt = w_trg + (size_t)b * H * F_IN;
    for (int i = threadIdx.x; i < H * F_IN; i += 256) {
        lws[i >> 8][i & 255] = gws[i];
        lwt[i >> 8][i & 255] = gwt[i];
    }
    __syncthreads();

    const int h = threadIdx.x & 7;
    const int g = threadIdx.x >> 3;            // 0..31
    const int row0 = tile * TILE_ROWS + g * 2;
    const int row1 = row0 + 1;
    const int r0c = row0 < NN ? row0 : NN - 1; // tail tile: clamp loads
    const int r1c = row1 < NN ? row1 : NN - 1;

    const fx4* __restrict__ rp0 = (const fx4*)(ch + ((size_t)b * NN + r0c) * F_IN);
    const fx4* __restrict__ rp1 = (const fx4*)(ch + ((size_t)b * NN + r1c) * F_IN);
    const fx4* __restrict__ ws4 = (const fx4*)(&lws[h][0]);
    const fx4* __restrict__ wt4 = (const fx4*)(&lwt[h][0]);

    fx4 a0s = {0.f, 0.f, 0.f, 0.f}, a0t = {0.f, 0.f, 0.f, 0.f};
    fx4 a1s = {0.f, 0.f, 0.f, 0.f}, a1t = {0.f, 0.f, 0.f, 0.f};

#pragma unroll 4
    for (int f4 = 0; f4 < F_IN / 4; ++f4) {
        const fx4 s = ws4[f4];
        const fx4 t = wt4[f4];
        const fx4 c0 = __builtin_nontemporal_load(&rp0[f4]);
        const fx4 c1 = __builtin_nontemporal_load(&rp1[f4]);
        a0s += c0 * s;
        a0t += c0 * t;
        a1s += c1 * s;
        a1t += c1 * t;
    }

    const float s0 = (a0s.x + a0s.y) + (a0s.z + a0s.w);
    const float t0 = (a0t.x + a0t.y) + (a0t.z + a0t.w);
    const float s1 = (a1s.x + a1s.y) + (a1s.z + a1s.w);
    const float t1 = (a1t.x + a1t.y) + (a1t.z + a1t.w);

    if (row0 < NN) {
        const size_t oi = ((size_t)b * NN + row0) * H + h;
        sc_src[oi] = (half_t)s0;
        sc_trg[oi] = (half_t)t0;
    }
    if (row1 < NN) {
        const size_t oi = ((size_t)b * NN + row1) * H + h;
        sc_src[oi] = (half_t)s1;
        sc_trg[oi] = (half_t)t1;
    }
}

// ---------------------------------------------------------------------------
// Kernel 3: lift (global gather) + sigmoid. 4 edges per thread. Indices and
// output are streamed non-temporally so the fp16 score tables (5.1 MB total)
// stay resident in L2/L3 for the random gathers.
// ---------------------------------------------------------------------------
__global__ __launch_bounds__(256) void gather_sigmoid(
        const ix4* __restrict__ head4,
        const ix4* __restrict__ tail4,
        const half_t* __restrict__ sc_src,
        const half_t* __restrict__ sc_trg,
        fx4* __restrict__ out4, int total4) {
    const int i = blockIdx.x * 256 + threadIdx.x;
    if (i < total4) {
        const ix4 hh = __builtin_nontemporal_load(&head4[i]);
        const ix4 tt = __builtin_nontemporal_load(&tail4[i]);
        fx4 r;
        r.x = (float)sc_src[hh.x] + (float)sc_trg[tt.x];
        r.y = (float)sc_src[hh.y] + (float)sc_trg[tt.y];
        r.z = (float)sc_src[hh.z] + (float)sc_trg[tt.z];
        r.w = (float)sc_src[hh.w] + (float)sc_trg[tt.w];
        r.x = 1.f / (1.f + __expf(-r.x));
        r.y = 1.f / (1.f + __expf(-r.y));
        r.z = 1.f / (1.f + __expf(-r.z));
        r.w = 1.f / (1.f + __expf(-r.w));
        __builtin_nontemporal_store(r, &out4[i]);
    }
}

extern "C" void kernel_launch(void* const* d_in, const int* in_sizes, int n_in,
                              void* d_out, int out_size, void* d_ws, size_t ws_size,
                              hipStream_t stream) {
    const float* ch   = (const float*)d_in[0];   // [8][20000][256] f32
    const int*   head = (const int*)d_in[1];     // [8][160000] int
    const int*   tail = (const int*)d_in[2];     // [8][160000] int
    const float* W    = (const float*)d_in[3];   // [512][256] f32
    const float* ssrc = (const float*)d_in[4];   // [8][1][8][64] f32
    const float* strg = (const float*)d_in[5];   // [8][1][8][64] f32
    float* out = (float*)d_out;                  // [8][160000] f32

    float* ws = (float*)d_ws;
    float* w_src  = ws;                                   // 16384 floats
    float* w_trg  = ws + BSZ * H * F_IN;                  // 16384 floats
    half_t* sc_src = (half_t*)(ws + 2 * BSZ * H * F_IN);  // 1,280,000 halves
    half_t* sc_trg = sc_src + (size_t)BSZ * NN * H;       // 1,280,000 halves

    fold_weights<<<BSZ * H, 256, 0, stream>>>(W, ssrc, strg, w_src, w_trg);
    node_scores<<<BSZ * NT_TILES, 256, 0, stream>>>(ch, w_src, w_trg, sc_src, sc_trg);
    const int total4 = (BSZ * E) / 4;                     // 320000
    gather_sigmoid<<<(total4 + 255) / 256, 256, 0, stream>>>(
        (const ix4*)head, (const ix4*)tail, sc_src, sc_trg, (fx4*)out, total4);
}

// Round 4
// 250.201 us; speedup vs baseline: 6.0299x; 1.2823x over previous
//
#include <hip/hip_runtime.h>
#include <math.h>

#define BSZ 8
#define NN 20000
#define F_IN 256
#define H 8
#define D 64
#define E 160000

typedef _Float16 half_t;
typedef float  fx4 __attribute__((ext_vector_type(4)));
typedef int    ix4 __attribute__((ext_vector_type(4)));
typedef _Float16 hx8 __attribute__((ext_vector_type(8)));
typedef _Float16 hx4 __attribute__((ext_vector_type(4)));

// ---------------------------------------------------------------------------
// Kernel 1: fold W_proj with the per-(b,h) scoring vectors, output fp16.
//   w16[b][n][f], n in [0,16): n<8 -> src head n; n>=8 -> trg head n-8.
//   w16 feeds node_scores' MFMA B-fragments directly ([N][K] row-major).
// ---------------------------------------------------------------------------
__global__ __launch_bounds__(256) void fold_weights(
        const float* __restrict__ W_proj,   // [H*D][F_IN]
        const float* __restrict__ s_src,    // [BSZ][1][H][D]
        const float* __restrict__ s_trg,
        half_t* __restrict__ w16) {         // [BSZ][16][F_IN] fp16
    __shared__ float ls[D];
    __shared__ float lt[D];
    const int b = blockIdx.x >> 3;
    const int h = blockIdx.x & 7;
    const int f = threadIdx.x;
    if (threadIdx.x < D) {
        ls[threadIdx.x] = s_src[((size_t)b * H + h) * D + threadIdx.x];
        lt[threadIdx.x] = s_trg[((size_t)b * H + h) * D + threadIdx.x];
    }
    __syncthreads();
    float as = 0.f, at = 0.f;
#pragma unroll 8
    for (int d = 0; d < D; ++d) {
        const float wp = W_proj[((size_t)(h * D + d)) * F_IN + f];  // coalesced over f
        as = fmaf(wp, ls[d], as);
        at = fmaf(wp, lt[d], at);
    }
    w16[((size_t)b * 16 + h) * F_IN + f]     = (half_t)as;   // src: n = h
    w16[((size_t)b * 16 + 8 + h) * F_IN + f] = (half_t)at;   // trg: n = 8+h
}

// ---------------------------------------------------------------------------
// Kernel 2: node scores as a skinny GEMM on the matrix cores.
//   scores[160K x 16] = ch[160K x 256] * w16[16 x 256]^T  (fp16 in, f32 acc)
// R3 post-mortem: vector-ALU versions are bound by 8x h-redundant reads
// (LDS-instr or scattered-L1). MFMA reads each operand once and reduces K
// in hardware. Per wave, per 16-row tile:
//   - 16 coalesced fp32 row loads (1 KB/instr, nontemporal) -> cvt fp16
//   - 16 ds_write_b64 into an XOR-swizzled [16][256] fp16 A-tile
//     (swizzle ^((row&7)<<4): row-major stride-512B would be a 16-way
//     bank conflict on the b128 fragment reads -- guide G4/T2)
//   - 8 x { ds_read_b128 A-frag + mfma_f32_16x16x32_f16 }, acc chained
//   - epilogue: C frag (col n=lane&15, row=(lane>>4)*4+reg, m89-verified
//     layout) -> fp16 stores split src/trg
// B-frags (all 16 weight vectors, K=256) live in 32 VGPR for the whole
// kernel. Wave-private 8 KB LDS tile -> NO barriers. 10000 tiles exactly.
// Expected limiter: the 164 MB fp32 stream at HBM rate.
// fp16 (11-bit mantissa) adds ~3e-5 output error, well under the passing
// 0.0039 absmax; bf16 would be ~10x riskier.
// ---------------------------------------------------------------------------
#define TROWS 16
#define TILES_PER_B (NN / TROWS)        // 1250 (exact)
#define TOTAL_TILES (BSZ * TILES_PER_B) // 10000

__global__ __launch_bounds__(256) void node_scores(
        const float* __restrict__ ch,      // [BSZ][NN][F_IN] f32
        const half_t* __restrict__ w16,    // [BSZ][16][F_IN] fp16
        half_t* __restrict__ sc_src,       // [BSZ*NN*H] fp16
        half_t* __restrict__ sc_trg) {
    __shared__ _Float16 lds_all[4][TROWS * F_IN];   // 4 waves x 8 KB = 32 KB

    const int wave = threadIdx.x >> 6;
    const int lane = threadIdx.x & 63;
    const int tile = blockIdx.x * 4 + wave;          // grid*4 == TOTAL_TILES
    const int b    = tile / TILES_PER_B;
    const int row0 = (tile % TILES_PER_B) * TROWS;

    char* lbase = (char*)&lds_all[wave][0];

    const int n    = lane & 15;   // output column (B and C share this)
    const int kgrp = lane >> 4;   // k-group 0..3

    // B-fragments: lane holds w16[b][n][s*32 + kgrp*8 .. +8) per k-step s.
    hx8 bf[8];
    {
        const half_t* wb = w16 + ((size_t)b * 16 + n) * F_IN + kgrp * 8;
#pragma unroll
        for (int s = 0; s < 8; ++s)
            bf[s] = *(const hx8*)(wb + s * 32);
    }

    // Stage 16 rows: coalesced fp32 (lane*16B of row i), cvt, swizzled write.
    const float* gsrc = ch + ((size_t)b * NN + row0) * F_IN;
#pragma unroll
    for (int i = 0; i < TROWS; ++i) {
        const fx4 v = __builtin_nontemporal_load(
            (const fx4*)(gsrc + (size_t)i * F_IN) + lane);
        hx4 h4;
        h4.x = (half_t)v.x; h4.y = (half_t)v.y;
        h4.z = (half_t)v.z; h4.w = (half_t)v.w;
        const int off = (i * 512 + lane * 8) ^ ((i & 7) << 4);
        *(hx4*)(lbase + off) = h4;
    }

    // K-loop: A-frag = row (lane&15), k = s*32 + kgrp*8 .. +8 (16B read).
    fx4 acc = {0.f, 0.f, 0.f, 0.f};
#pragma unroll
    for (int s = 0; s < 8; ++s) {
        const int off = ((lane & 15) * 512 + s * 64 + kgrp * 16)
                        ^ ((lane & 7) << 4);         // (row&7) == lane&7 here
        const hx8 af = *(const hx8*)(lbase + off);
        acc = __builtin_amdgcn_mfma_f32_16x16x32_f16(af, bf[s], acc, 0, 0, 0);
    }

    // Epilogue: C[m][n], m = kgrp*4 + r (m89 layout), n = lane&15.
#pragma unroll
    for (int r = 0; r < 4; ++r) {
        const int row = row0 + kgrp * 4 + r;
        const half_t val = (half_t)acc[r];
        if (n < 8) sc_src[((size_t)b * NN + row) * H + n]       = val;
        else       sc_trg[((size_t)b * NN + row) * H + (n - 8)] = val;
    }
}

// ---------------------------------------------------------------------------
// Kernel 3: lift (global gather) + sigmoid. 4 edges per thread. Indices and
// output are streamed non-temporally so the fp16 score tables (5.1 MB total)
// stay resident in L2/L3 for the random gathers.
// ---------------------------------------------------------------------------
__global__ __launch_bounds__(256) void gather_sigmoid(
        const ix4* __restrict__ head4,
        const ix4* __restrict__ tail4,
        const half_t* __restrict__ sc_src,
        const half_t* __restrict__ sc_trg,
        fx4* __restrict__ out4, int total4) {
    const int i = blockIdx.x * 256 + threadIdx.x;
    if (i < total4) {
        const ix4 hh = __builtin_nontemporal_load(&head4[i]);
        const ix4 tt = __builtin_nontemporal_load(&tail4[i]);
        fx4 r;
        r.x = (float)sc_src[hh.x] + (float)sc_trg[tt.x];
        r.y = (float)sc_src[hh.y] + (float)sc_trg[tt.y];
        r.z = (float)sc_src[hh.z] + (float)sc_trg[tt.z];
        r.w = (float)sc_src[hh.w] + (float)sc_trg[tt.w];
        r.x = 1.f / (1.f + __expf(-r.x));
        r.y = 1.f / (1.f + __expf(-r.y));
        r.z = 1.f / (1.f + __expf(-r.z));
        r.w = 1.f / (1.f + __expf(-r.w));
        __builtin_nontemporal_store(r, &out4[i]);
    }
}

extern "C" void kernel_launch(void* const* d_in, const int* in_sizes, int n_in,
                              void* d_out, int out_size, void* d_ws, size_t ws_size,
                              hipStream_t stream) {
    const float* ch   = (const float*)d_in[0];   // [8][20000][256] f32
    const int*   head = (const int*)d_in[1];     // [8][160000] int
    const int*   tail = (const int*)d_in[2];     // [8][160000] int
    const float* W    = (const float*)d_in[3];   // [512][256] f32
    const float* ssrc = (const float*)d_in[4];   // [8][1][8][64] f32
    const float* strg = (const float*)d_in[5];   // [8][1][8][64] f32
    float* out = (float*)d_out;                  // [8][160000] f32

    char* base = (char*)d_ws;
    half_t* w16    = (half_t*)base;                       // 8*16*256*2 = 64 KB
    half_t* sc_src = (half_t*)(base + 65536);             // 2.56 MB
    half_t* sc_trg = sc_src + (size_t)BSZ * NN * H;       // 2.56 MB

    fold_weights<<<BSZ * H, 256, 0, stream>>>(W, ssrc, strg, w16);
    node_scores<<<TOTAL_TILES / 4, 256, 0, stream>>>(ch, w16, sc_src, sc_trg);
    const int total4 = (BSZ * E) / 4;                     // 320000
    gather_sigmoid<<<(total4 + 255) / 256, 256, 0, stream>>>(
        (const ix4*)head, (const ix4*)tail, sc_src, sc_trg, (fx4*)out, total4);
}